// Round 6
// baseline (66.393 us; speedup 1.0000x reference)
//
#include <hip/hip_runtime.h>
#include <math.h>

#define BB 16
#define TT 1024
#define T1 1025
#define DD 512

__device__ __forceinline__ float fract_exact(float x) {
#if defined(__has_builtin)
#if __has_builtin(__builtin_amdgcn_fractf)
    return __builtin_amdgcn_fractf(x);     // v_fract_f32: x - floor(x), exact
#else
    return x - floorf(x);
#endif
#else
    return x - floorf(x);
#endif
}

// ---------------- Kernel 1: alphas = sigmoid(hidden @ w + b) ----------------
// one 64-lane wave per (b,t) row; 4 waves per 256-thread block
__global__ __launch_bounds__(256) void alpha_kernel(
    const float* __restrict__ hidden,   // [B, T, D]
    const float* __restrict__ w,        // [D]
    const float* __restrict__ bias,     // [1]
    float* __restrict__ alphas_out)     // [B, T1]  (t < T written here)
{
    int row  = blockIdx.x * 4 + (threadIdx.x >> 6);   // 0 .. B*T-1
    int lane = threadIdx.x & 63;
    const float* h = hidden + (size_t)row * DD;
    float4 x0 = *(const float4*)(h + lane * 4);
    float4 x1 = *(const float4*)(h + 256 + lane * 4);
    float4 w0 = *(const float4*)(w + lane * 4);
    float4 w1 = *(const float4*)(w + 256 + lane * 4);
    float s = x0.x * w0.x + x0.y * w0.y + x0.z * w0.z + x0.w * w0.w
            + x1.x * w1.x + x1.y * w1.y + x1.z * w1.z + x1.w * w1.w;
    #pragma unroll
    for (int off = 32; off > 0; off >>= 1) s += __shfl_down(s, off, 64);
    if (lane == 0) {
        float x = s + bias[0];
        float sig = 1.0f / (1.0f + expf(-x));
        int b = row >> 10;       // / TT
        int t = row & 1023;      // % TT
        alphas_out[b * T1 + t] = sig;
    }
}

// ---------------- Kernel 2: CIF scan — 16 chains in 16 lanes of one wave ----
// 1 block x 256 threads. Wave 0 lanes 0..15 each run one batch's serial chain
//   ni = integrate + a;  peak[t] = ni;  integrate = fract(ni)   (bit-exact)
// with alphas loaded from global (L2-hot) via an 8-slot float4 rotating
// register buffer (32-step prefetch distance) and peaks stored to global
// every 4 steps. Aux instructions are amortized 16x across the chains.
// Waves 1..3 concurrently: token_num + alphas tail zeros.
// After barrier: 4 waves x 4 batches ballot-compact fire times.
__global__ __launch_bounds__(256) void scan_kernel(
    float* __restrict__ alphas_out,   // [B, T1]
    float* __restrict__ token_num,    // [B]
    float* __restrict__ cif_peak,     // [B, T1]
    int*   __restrict__ fire_time,    // ws [B, T1]
    int*   __restrict__ nfired)       // ws [B]
{
    int tid  = threadIdx.x;
    int wv   = tid >> 6;
    int lane = tid & 63;

    if (wv == 0) {
        if (lane < 16) {
            int b = lane;
            const float* a_b  = alphas_out + b * T1;
            float*       pk_b = cif_peak   + b * T1;

            float4 buf[8];                       // steps 0..31
            #pragma unroll
            for (int k = 0; k < 8; ++k) buf[k] = *(const float4*)(a_b + 4 * k);

            float integrate = 0.0f;
            #pragma unroll 8                     // i&7 static -> regs, no scratch
            for (int i = 0; i < 256; ++i) {
                float4 A = buf[i & 7];
                if (i < 248)                     // wave-uniform branch
                    buf[i & 7] = *(const float4*)(a_b + 4 * i + 32);
                float4 P;
                float n0 = integrate + A.x; P.x = n0; float i0 = fract_exact(n0);
                float n1 = i0 + A.y;        P.y = n1; float i1 = fract_exact(n1);
                float n2 = i1 + A.z;        P.z = n2; float i2 = fract_exact(n2);
                float n3 = i2 + A.w;        P.w = n3; integrate = fract_exact(n3);
                *(float4*)(pk_b + 4 * i) = P;
            }
            // tail step: alpha = 0 -> ni == integrate (< 1, never fires)
            pk_b[TT] = integrate;
        }
    } else {
        // waves 1..3: token_num = floor(sum alphas) per batch (double accum),
        // batches round-robin: wave w -> b = (w-1) + 3k
        for (int b = wv - 1; b < BB; b += 3) {
            const float* a_b = alphas_out + b * T1;
            double s = 0.0;
            for (int t = lane; t < TT; t += 64) s += (double)a_b[t];
            #pragma unroll
            for (int off = 32; off > 0; off >>= 1) s += __shfl_down(s, off, 64);
            if (lane == 0) token_num[b] = (float)floor(s);
        }
        if (wv == 1 && lane < BB) alphas_out[lane * T1 + TT] = 0.0f;  // tail col
    }
    __syncthreads();   // drains vmcnt -> peaks visible block-wide

    // fire-time compaction: wave w handles batches 4w..4w+3; fire == peak>=1
    for (int b = wv * 4; b < wv * 4 + 4; ++b) {
        const float* pk_b = cif_peak + b * T1;
        int* ft_b = fire_time + b * T1;
        int cnt = 0;
        for (int base = 0; base < T1; base += 64) {
            int t = base + lane;
            bool f = (t < T1) && (pk_b[t] >= 1.0f);
            unsigned long long m = __ballot(f);
            int pos = cnt + __popcll(m & ((1ull << lane) - 1ull));
            if (f) ft_b[pos] = t;
            cnt += __popcll(m);
        }
        if (lane == 0) nfired[b] = cnt;
    }
}

// ---------------- Kernel 3: segmented weighted sums -> packed frames --------
// one block per (b, j) output row; 128 threads x float4 = 512 floats.
// cur/rem reconstructed exactly from (peak, alpha):
//   integrate_prev(t) = peak[t-1] >= 1 ? peak[t-1]-1 : peak[t-1]   (exact)
//   cur(fire t)       = 1 - integrate_prev(t)
//   interior cur(t)   = alpha[t]
//   rem(s)            = alpha[s] - cur(s)
__global__ __launch_bounds__(128) void fill_kernel(
    const float* __restrict__ hidden,     // [B, T, D]
    const float* __restrict__ alphas,     // [B, T1] (output buffer)
    const float* __restrict__ peak,       // [B, T1] (cif_peak output)
    const int*   __restrict__ fire_time,  // ws [B, T1]
    const int*   __restrict__ nfired,     // ws [B]
    float* __restrict__ ae)               // [B, T1, D]
{
    int idx = blockIdx.x;
    int b = idx / T1;
    int j = idx % T1;
    int d = threadIdx.x * 4;
    float4* out4 = (float4*)(ae + ((size_t)b * T1 + j) * DD + d);

    int nf = nfired[b];
    if (j >= nf) {                        // unfired slot: zeros
        *out4 = make_float4(0.f, 0.f, 0.f, 0.f);
        return;
    }
    const int*   ft_b = fire_time + b * T1;
    const float* a_b  = alphas + b * T1;
    const float* pk_b = peak + b * T1;
    const float* hb   = hidden + (size_t)b * TT * DD + d;

    int e = ft_b[j];                      // fire time of this token
    float4 acc = make_float4(0.f, 0.f, 0.f, 0.f);
    int t0;
    if (j > 0) {
        int s = ft_b[j - 1];              // previous fire time
        float ps   = (s > 0) ? pk_b[s - 1] : 0.0f;
        float ips  = (ps >= 1.0f) ? ps - 1.0f : ps;   // integrate before step s
        float curs = 1.0f - ips;                      // dist_completion at s
        float r    = a_b[s] - curs;                   // remainds at s
        float4 h = *(const float4*)(hb + (size_t)s * DD);
        acc.x = r * h.x; acc.y = r * h.y; acc.z = r * h.z; acc.w = r * h.w;
        t0 = s + 1;
    } else {
        t0 = 0;
    }
    for (int t = t0; t < e; ++t) {        // interior rows: cur = alpha
        float c = a_b[t];
        float4 h = *(const float4*)(hb + (size_t)t * DD);
        acc.x += c * h.x; acc.y += c * h.y; acc.z += c * h.z; acc.w += c * h.w;
    }
    {   // final row t = e (the fire): cur = 1 - integrate_prev(e)
        float pe  = (e > 0) ? pk_b[e - 1] : 0.0f;
        float ipe = (pe >= 1.0f) ? pe - 1.0f : pe;
        float ce  = 1.0f - ipe;
        float4 h = *(const float4*)(hb + (size_t)e * DD);
        acc.x += ce * h.x; acc.y += ce * h.y; acc.z += ce * h.z; acc.w += ce * h.w;
    }
    *out4 = acc;
}

extern "C" void kernel_launch(void* const* d_in, const int* in_sizes, int n_in,
                              void* d_out, int out_size, void* d_ws, size_t ws_size,
                              hipStream_t stream) {
    const float* hidden = (const float*)d_in[0];
    const float* w      = (const float*)d_in[1];
    const float* bias   = (const float*)d_in[2];

    float* out        = (float*)d_out;
    float* ae         = out;                                   // [B,T1,D]
    float* token_num  = out + (size_t)BB * T1 * DD;            // [B]
    float* alphas_out = token_num + BB;                        // [B,T1]
    float* cif_peak   = alphas_out + (size_t)BB * T1;          // [B,T1]

    int* fire_time = (int*)d_ws;                               // [B,T1]
    int* nfired    = fire_time + (size_t)BB * T1;              // [B]

    alpha_kernel<<<(BB * TT) / 4, 256, 0, stream>>>(hidden, w, bias, alphas_out);
    scan_kernel<<<1, 256, 0, stream>>>(alphas_out, token_num, cif_peak,
                                       fire_time, nfired);
    fill_kernel<<<BB * T1, 128, 0, stream>>>(hidden, alphas_out, cif_peak,
                                             fire_time, nfired, ae);
}

// Round 7
// 52.339 us; speedup vs baseline: 1.2685x; 1.2685x over previous
//
#include <hip/hip_runtime.h>
#include <math.h>

#define BB 16
#define TT 1024
#define T1 1025
#define ASTRIDE 1060   // LDS row stride (floats): 1060%32==4 -> 2-way bank alias (free)

__device__ __forceinline__ float fract_exact(float x) {
#if defined(__has_builtin)
#if __has_builtin(__builtin_amdgcn_fractf)
    return __builtin_amdgcn_fractf(x);     // v_fract_f32: x - floor(x), exact
#else
    return x - floorf(x);
#endif
#else
    return x - floorf(x);
#endif
}

#define DD 512

// ---------------- Kernel 1: alphas = sigmoid(hidden @ w + b) ----------------
__global__ __launch_bounds__(256) void alpha_kernel(
    const float* __restrict__ hidden,   // [B, T, D]
    const float* __restrict__ w,        // [D]
    const float* __restrict__ bias,     // [1]
    float* __restrict__ alphas_out)     // [B, T1]
{
    int row  = blockIdx.x * 4 + (threadIdx.x >> 6);   // 0 .. B*T-1
    int lane = threadIdx.x & 63;
    const float* h = hidden + (size_t)row * DD;
    float4 x0 = *(const float4*)(h + lane * 4);
    float4 x1 = *(const float4*)(h + 256 + lane * 4);
    float4 w0 = *(const float4*)(w + lane * 4);
    float4 w1 = *(const float4*)(w + 256 + lane * 4);
    float s = x0.x * w0.x + x0.y * w0.y + x0.z * w0.z + x0.w * w0.w
            + x1.x * w1.x + x1.y * w1.y + x1.z * w1.z + x1.w * w1.w;
    #pragma unroll
    for (int off = 32; off > 0; off >>= 1) s += __shfl_down(s, off, 64);
    if (lane == 0) {
        float x = s + bias[0];
        float sig = 1.0f / (1.0f + expf(-x));
        int b = row >> 10;
        int t = row & 1023;
        alphas_out[b * T1 + t] = sig;
    }
}

// ---------------- Kernel 2: CIF scan — 16 chains in 16 lanes of one wave ----
// 1 block x 256 threads. All alphas staged to LDS (coalesced, zero-padded).
// Wave 0 lanes 0..15: per-lane serial chain with NAMED float4 register banks
// (c0..c7 / n0..n7, double-buffered 32-step phases; no arrays -> no scratch).
//   ni = integrate + a;  peak[t] = ni;  integrate = fract(ni)   (bit-exact)
// Peaks stored straight to global (vmcnt), LDS loads on lgkmcnt -> no false
// waits. Waves 1..3: token_num from LDS concurrently. Then ballot compaction.
__global__ __launch_bounds__(256) void scan_kernel(
    float* __restrict__ alphas_out,   // [B, T1]
    float* __restrict__ token_num,    // [B]
    float* __restrict__ cif_peak,     // [B, T1]
    int*   __restrict__ fire_time,    // ws [B, T1]
    int*   __restrict__ nfired)       // ws [B]
{
    int tid  = threadIdx.x;
    int wv   = tid >> 6;
    int lane = tid & 63;

    __shared__ float a_sh[BB][ASTRIDE];

    // cooperative stage: wave w handles rows w, w+4, ... (coalesced per row)
    for (int r = wv; r < BB; r += 4) {
        const float* src = alphas_out + r * T1;
        for (int t = lane; t < TT; t += 64)           a_sh[r][t] = src[t];
        for (int t = TT + lane; t < ASTRIDE; t += 64) a_sh[r][t] = 0.0f;
    }
    __syncthreads();

    if (wv == 0) {
        if (lane < BB) {
            const float* arow = a_sh[lane];
            float*       pk   = cif_peak + lane * T1;
            float integrate = 0.0f;
            float4 c0, c1, c2, c3, c4, c5, c6, c7;
            float4 n0, n1, n2, n3, n4, n5, n6, n7;

#define LD(OFF) (*(const float4*)(arow + (OFF)))
#define CH4(A, S) {                                                   \
            float4 P;                                                 \
            float q0 = integrate + (A).x; P.x = q0; float j0 = fract_exact(q0); \
            float q1 = j0 + (A).y;        P.y = q1; float j1 = fract_exact(q1); \
            float q2 = j1 + (A).z;        P.z = q2; float j2 = fract_exact(q2); \
            float q3 = j2 + (A).w;        P.w = q3; integrate = fract_exact(q3); \
            *(float4*)(pk + (S)) = P; }

            // preload steps 0..31
            c0 = LD(0);  c1 = LD(4);  c2 = LD(8);  c3 = LD(12);
            c4 = LD(16); c5 = LD(20); c6 = LD(24); c7 = LD(28);

            for (int m = 0; m < 16; ++m) {
                int s = m * 64;
                // prefetch steps s+32..s+63 into n-bank
                n0 = LD(s + 32); n1 = LD(s + 36); n2 = LD(s + 40); n3 = LD(s + 44);
                n4 = LD(s + 48); n5 = LD(s + 52); n6 = LD(s + 56); n7 = LD(s + 60);
                // consume c-bank -> peaks s..s+31
                CH4(c0, s +  0) CH4(c1, s +  4) CH4(c2, s +  8) CH4(c3, s + 12)
                CH4(c4, s + 16) CH4(c5, s + 20) CH4(c6, s + 24) CH4(c7, s + 28)
                // prefetch steps s+64..s+95 into c-bank (zero pad keeps in-bounds)
                c0 = LD(s + 64); c1 = LD(s + 68); c2 = LD(s + 72); c3 = LD(s + 76);
                c4 = LD(s + 80); c5 = LD(s + 84); c6 = LD(s + 88); c7 = LD(s + 92);
                // consume n-bank -> peaks s+32..s+63
                CH4(n0, s + 32) CH4(n1, s + 36) CH4(n2, s + 40) CH4(n3, s + 44)
                CH4(n4, s + 48) CH4(n5, s + 52) CH4(n6, s + 56) CH4(n7, s + 60)
            }
#undef CH4
#undef LD
            // tail step: alpha = 0 -> ni == integrate (< 1, never fires)
            pk[TT] = integrate;
        }
    } else {
        // waves 1..3: token_num = floor(sum alphas) from LDS; wave1 zeros tail col
        for (int b = wv - 1; b < BB; b += 3) {
            double s = 0.0;
            for (int t = lane; t < TT; t += 64) s += (double)a_sh[b][t];
            #pragma unroll
            for (int off = 32; off > 0; off >>= 1) s += __shfl_down(s, off, 64);
            if (lane == 0) token_num[b] = (float)floor(s);
        }
        if (wv == 1 && lane < BB) alphas_out[lane * T1 + TT] = 0.0f;
    }
    __syncthreads();   // drains wave0's vmcnt -> peaks visible (same CU L1)

    // fire-time compaction: wave w -> batches 4w..4w+3; fire == peak >= 1
    for (int b = wv * 4; b < wv * 4 + 4; ++b) {
        const float* pk_b = cif_peak + b * T1;
        int* ft_b = fire_time + b * T1;
        int cnt = 0;
        for (int base = 0; base < T1; base += 64) {
            int t = base + lane;
            bool f = (t < T1) && (pk_b[t] >= 1.0f);
            unsigned long long m = __ballot(f);
            int pos = cnt + __popcll(m & ((1ull << lane) - 1ull));
            if (f) ft_b[pos] = t;
            cnt += __popcll(m);
        }
        if (lane == 0) nfired[b] = cnt;
    }
}

// ---------------- Kernel 3: segmented weighted sums -> packed frames --------
// one block per (b, j) output row; 128 threads x float4 = 512 floats.
// cur/rem reconstructed exactly from (peak, alpha):
//   integrate_prev(t) = peak[t-1] >= 1 ? peak[t-1]-1 : peak[t-1]   (exact)
//   cur(fire t)       = 1 - integrate_prev(t)
//   interior cur(t)   = alpha[t]
//   rem(s)            = alpha[s] - cur(s)
__global__ __launch_bounds__(128) void fill_kernel(
    const float* __restrict__ hidden,     // [B, T, D]
    const float* __restrict__ alphas,     // [B, T1]
    const float* __restrict__ peak,       // [B, T1]
    const int*   __restrict__ fire_time,  // ws [B, T1]
    const int*   __restrict__ nfired,     // ws [B]
    float* __restrict__ ae)               // [B, T1, D]
{
    int idx = blockIdx.x;
    int b = idx / T1;
    int j = idx % T1;
    int d = threadIdx.x * 4;
    float4* out4 = (float4*)(ae + ((size_t)b * T1 + j) * DD + d);

    int nf = nfired[b];
    if (j >= nf) {                        // unfired slot: zeros
        *out4 = make_float4(0.f, 0.f, 0.f, 0.f);
        return;
    }
    const int*   ft_b = fire_time + b * T1;
    const float* a_b  = alphas + b * T1;
    const float* pk_b = peak + b * T1;
    const float* hb   = hidden + (size_t)b * TT * DD + d;

    int e = ft_b[j];                      // fire time of this token
    float4 acc = make_float4(0.f, 0.f, 0.f, 0.f);
    int t0;
    if (j > 0) {
        int s = ft_b[j - 1];              // previous fire time
        float ps   = (s > 0) ? pk_b[s - 1] : 0.0f;
        float ips  = (ps >= 1.0f) ? ps - 1.0f : ps;   // integrate before step s
        float curs = 1.0f - ips;                      // dist_completion at s
        float r    = a_b[s] - curs;                   // remainds at s
        float4 h = *(const float4*)(hb + (size_t)s * DD);
        acc.x = r * h.x; acc.y = r * h.y; acc.z = r * h.z; acc.w = r * h.w;
        t0 = s + 1;
    } else {
        t0 = 0;
    }
    for (int t = t0; t < e; ++t) {        // interior rows: cur = alpha
        float c = a_b[t];
        float4 h = *(const float4*)(hb + (size_t)t * DD);
        acc.x += c * h.x; acc.y += c * h.y; acc.z += c * h.z; acc.w += c * h.w;
    }
    {   // final row t = e (the fire): cur = 1 - integrate_prev(e)
        float pe  = (e > 0) ? pk_b[e - 1] : 0.0f;
        float ipe = (pe >= 1.0f) ? pe - 1.0f : pe;
        float ce  = 1.0f - ipe;
        float4 h = *(const float4*)(hb + (size_t)e * DD);
        acc.x += ce * h.x; acc.y += ce * h.y; acc.z += ce * h.z; acc.w += ce * h.w;
    }
    *out4 = acc;
}

extern "C" void kernel_launch(void* const* d_in, const int* in_sizes, int n_in,
                              void* d_out, int out_size, void* d_ws, size_t ws_size,
                              hipStream_t stream) {
    const float* hidden = (const float*)d_in[0];
    const float* w      = (const float*)d_in[1];
    const float* bias   = (const float*)d_in[2];

    float* out        = (float*)d_out;
    float* ae         = out;                                   // [B,T1,D]
    float* token_num  = out + (size_t)BB * T1 * DD;            // [B]
    float* alphas_out = token_num + BB;                        // [B,T1]
    float* cif_peak   = alphas_out + (size_t)BB * T1;          // [B,T1]

    int* fire_time = (int*)d_ws;                               // [B,T1]
    int* nfired    = fire_time + (size_t)BB * T1;              // [B]

    alpha_kernel<<<(BB * TT) / 4, 256, 0, stream>>>(hidden, w, bias, alphas_out);
    scan_kernel<<<1, 256, 0, stream>>>(alphas_out, token_num, cif_peak,
                                       fire_time, nfired);
    fill_kernel<<<BB * T1, 128, 0, stream>>>(hidden, alphas_out, cif_peak,
                                             fire_time, nfired, ae);
}

// Round 8
// 40.916 us; speedup vs baseline: 1.6226x; 1.2792x over previous
//
#include <hip/hip_runtime.h>
#include <math.h>

#define BB 16
#define TT 1024
#define T1 1025
#define DD 512
#define AST 1060   // LDS row stride (floats): %32==4 -> worst 2-way bank alias (free);
                   // %4==0 -> rows 16B-aligned for b128 LDS ops

__device__ __forceinline__ float fract_exact(float x) {
#if defined(__has_builtin)
#if __has_builtin(__builtin_amdgcn_fractf)
    return __builtin_amdgcn_fractf(x);     // v_fract_f32: x - floor(x), exact
#else
    return x - floorf(x);
#endif
#else
    return x - floorf(x);
#endif
}

// ---------------- Kernel 1: alphas = sigmoid(hidden @ w + b) ----------------
__global__ __launch_bounds__(256) void alpha_kernel(
    const float* __restrict__ hidden,   // [B, T, D]
    const float* __restrict__ w,        // [D]
    const float* __restrict__ bias,     // [1]
    float* __restrict__ alphas_out)     // [B, T1]
{
    int row  = blockIdx.x * 4 + (threadIdx.x >> 6);   // 0 .. B*T-1
    int lane = threadIdx.x & 63;
    const float* h = hidden + (size_t)row * DD;
    float4 x0 = *(const float4*)(h + lane * 4);
    float4 x1 = *(const float4*)(h + 256 + lane * 4);
    float4 w0 = *(const float4*)(w + lane * 4);
    float4 w1 = *(const float4*)(w + 256 + lane * 4);
    float s = x0.x * w0.x + x0.y * w0.y + x0.z * w0.z + x0.w * w0.w
            + x1.x * w1.x + x1.y * w1.y + x1.z * w1.z + x1.w * w1.w;
    #pragma unroll
    for (int off = 32; off > 0; off >>= 1) s += __shfl_down(s, off, 64);
    if (lane == 0) {
        float x = s + bias[0];
        float sig = 1.0f / (1.0f + expf(-x));
        int b = row >> 10;
        int t = row & 1023;
        alphas_out[b * T1 + t] = sig;
    }
}

// ---------------- Kernel 2: CIF scan — 16 chains in 16 lanes of one wave ----
// 1 block x 256 threads. Alphas staged to LDS; wave 0 lanes 0..15 run the 16
// serial chains with NAMED float4 register banks (c0..c7/n0..n7 double
// buffer; no arrays -> no scratch), peaks written to LDS (p_sh) with
// ds_write_b128 (2-way bank alias max = free). Waves 1..3: token_num.
// Then a fused pass per row: coalesced peak writeout + ballot fire
// compaction straight from LDS (no global round-trip).
__global__ __launch_bounds__(256) void scan_kernel(
    float* __restrict__ alphas_out,   // [B, T1]
    float* __restrict__ token_num,    // [B]
    float* __restrict__ cif_peak,     // [B, T1]
    int*   __restrict__ fire_time,    // ws [B, T1]
    int*   __restrict__ nfired)       // ws [B]
{
    int tid  = threadIdx.x;
    int wv   = tid >> 6;
    int lane = tid & 63;

    __shared__ float a_sh[BB][AST];
    __shared__ float p_sh[BB][AST];

    // cooperative stage: wave w handles rows w, w+4, ... (coalesced per row)
    for (int r = wv; r < BB; r += 4) {
        const float* src = alphas_out + r * T1;
        for (int t = lane; t < TT; t += 64)        a_sh[r][t] = src[t];
        for (int t = TT + lane; t < AST; t += 64)  a_sh[r][t] = 0.0f;
    }
    __syncthreads();

    if (wv == 0) {
        if (lane < BB) {
            const float* arow = a_sh[lane];
            float*       prow = p_sh[lane];
            float integrate = 0.0f;
            float4 c0, c1, c2, c3, c4, c5, c6, c7;
            float4 n0, n1, n2, n3, n4, n5, n6, n7;

#define LD(OFF) (*(const float4*)(arow + (OFF)))
#define CH4(A, S) {                                                   \
            float4 P;                                                 \
            float q0 = integrate + (A).x; P.x = q0; float j0 = fract_exact(q0); \
            float q1 = j0 + (A).y;        P.y = q1; float j1 = fract_exact(q1); \
            float q2 = j1 + (A).z;        P.z = q2; float j2 = fract_exact(q2); \
            float q3 = j2 + (A).w;        P.w = q3; integrate = fract_exact(q3); \
            *(float4*)(prow + (S)) = P; }

            // preload steps 0..31
            c0 = LD(0);  c1 = LD(4);  c2 = LD(8);  c3 = LD(12);
            c4 = LD(16); c5 = LD(20); c6 = LD(24); c7 = LD(28);

            for (int m = 0; m < 16; ++m) {
                int s = m * 64;
                // prefetch steps s+32..s+63 into n-bank
                n0 = LD(s + 32); n1 = LD(s + 36); n2 = LD(s + 40); n3 = LD(s + 44);
                n4 = LD(s + 48); n5 = LD(s + 52); n6 = LD(s + 56); n7 = LD(s + 60);
                // consume c-bank -> peaks s..s+31 (to LDS)
                CH4(c0, s +  0) CH4(c1, s +  4) CH4(c2, s +  8) CH4(c3, s + 12)
                CH4(c4, s + 16) CH4(c5, s + 20) CH4(c6, s + 24) CH4(c7, s + 28)
                // prefetch steps s+64..s+95 into c-bank (zero pad keeps in-bounds)
                c0 = LD(s + 64); c1 = LD(s + 68); c2 = LD(s + 72); c3 = LD(s + 76);
                c4 = LD(s + 80); c5 = LD(s + 84); c6 = LD(s + 88); c7 = LD(s + 92);
                // consume n-bank -> peaks s+32..s+63 (to LDS)
                CH4(n0, s + 32) CH4(n1, s + 36) CH4(n2, s + 40) CH4(n3, s + 44)
                CH4(n4, s + 48) CH4(n5, s + 52) CH4(n6, s + 56) CH4(n7, s + 60)
            }
#undef CH4
#undef LD
            // tail step: alpha = 0 -> ni == integrate (< 1, never fires)
            prow[TT] = integrate;
        }
    } else {
        // waves 1..3: token_num = floor(sum alphas) from LDS; wave1 zeros tail col
        for (int b = wv - 1; b < BB; b += 3) {
            double s = 0.0;
            for (int t = lane; t < TT; t += 64) s += (double)a_sh[b][t];
            #pragma unroll
            for (int off = 32; off > 0; off >>= 1) s += __shfl_down(s, off, 64);
            if (lane == 0) token_num[b] = (float)floor(s);
        }
        if (wv == 1 && lane < BB) alphas_out[lane * T1 + TT] = 0.0f;
    }
    __syncthreads();   // LDS writes visible block-wide

    // fused coalesced writeout + fire-time compaction; wave w -> rows 4w..4w+3
    for (int r = wv * 4; r < wv * 4 + 4; ++r) {
        float* pk_g = cif_peak + r * T1;
        int*   ft_b = fire_time + r * T1;
        int cnt = 0;
        for (int base = 0; base < T1; base += 64) {
            int t = base + lane;
            bool in = (t < T1);
            float p = in ? p_sh[r][t] : 0.0f;
            if (in) pk_g[t] = p;
            bool f = in && (p >= 1.0f);
            unsigned long long m = __ballot(f);
            int pos = cnt + __popcll(m & ((1ull << lane) - 1ull));
            if (f) ft_b[pos] = t;
            cnt += __popcll(m);
        }
        if (lane == 0) nfired[r] = cnt;
    }
}

// ---------------- Kernel 3: segmented weighted sums -> packed frames --------
// one block per (b, j) output row; 128 threads x float4 = 512 floats.
// cur/rem reconstructed exactly from (peak, alpha):
//   integrate_prev(t) = peak[t-1] >= 1 ? peak[t-1]-1 : peak[t-1]   (exact)
//   cur(fire t)       = 1 - integrate_prev(t)
//   interior cur(t)   = alpha[t]
//   rem(s)            = alpha[s] - cur(s)
__global__ __launch_bounds__(128) void fill_kernel(
    const float* __restrict__ hidden,     // [B, T, D]
    const float* __restrict__ alphas,     // [B, T1]
    const float* __restrict__ peak,       // [B, T1]
    const int*   __restrict__ fire_time,  // ws [B, T1]
    const int*   __restrict__ nfired,     // ws [B]
    float* __restrict__ ae)               // [B, T1, D]
{
    int idx = blockIdx.x;
    int b = idx / T1;
    int j = idx % T1;
    int d = threadIdx.x * 4;
    float4* out4 = (float4*)(ae + ((size_t)b * T1 + j) * DD + d);

    int nf = nfired[b];
    if (j >= nf) {                        // unfired slot: zeros
        *out4 = make_float4(0.f, 0.f, 0.f, 0.f);
        return;
    }
    const int*   ft_b = fire_time + b * T1;
    const float* a_b  = alphas + b * T1;
    const float* pk_b = peak + b * T1;
    const float* hb   = hidden + (size_t)b * TT * DD + d;

    int e = ft_b[j];                      // fire time of this token
    float4 acc = make_float4(0.f, 0.f, 0.f, 0.f);
    int t0;
    if (j > 0) {
        int s = ft_b[j - 1];              // previous fire time
        float ps   = (s > 0) ? pk_b[s - 1] : 0.0f;
        float ips  = (ps >= 1.0f) ? ps - 1.0f : ps;   // integrate before step s
        float curs = 1.0f - ips;                      // dist_completion at s
        float r    = a_b[s] - curs;                   // remainds at s
        float4 h = *(const float4*)(hb + (size_t)s * DD);
        acc.x = r * h.x; acc.y = r * h.y; acc.z = r * h.z; acc.w = r * h.w;
        t0 = s + 1;
    } else {
        t0 = 0;
    }
    for (int t = t0; t < e; ++t) {        // interior rows: cur = alpha
        float c = a_b[t];
        float4 h = *(const float4*)(hb + (size_t)t * DD);
        acc.x += c * h.x; acc.y += c * h.y; acc.z += c * h.z; acc.w += c * h.w;
    }
    {   // final row t = e (the fire): cur = 1 - integrate_prev(e)
        float pe  = (e > 0) ? pk_b[e - 1] : 0.0f;
        float ipe = (pe >= 1.0f) ? pe - 1.0f : pe;
        float ce  = 1.0f - ipe;
        float4 h = *(const float4*)(hb + (size_t)e * DD);
        acc.x += ce * h.x; acc.y += ce * h.y; acc.z += ce * h.z; acc.w += ce * h.w;
    }
    *out4 = acc;
}

extern "C" void kernel_launch(void* const* d_in, const int* in_sizes, int n_in,
                              void* d_out, int out_size, void* d_ws, size_t ws_size,
                              hipStream_t stream) {
    const float* hidden = (const float*)d_in[0];
    const float* w      = (const float*)d_in[1];
    const float* bias   = (const float*)d_in[2];

    float* out        = (float*)d_out;
    float* ae         = out;                                   // [B,T1,D]
    float* token_num  = out + (size_t)BB * T1 * DD;            // [B]
    float* alphas_out = token_num + BB;                        // [B,T1]
    float* cif_peak   = alphas_out + (size_t)BB * T1;          // [B,T1]

    int* fire_time = (int*)d_ws;                               // [B,T1]
    int* nfired    = fire_time + (size_t)BB * T1;              // [B]

    alpha_kernel<<<(BB * TT) / 4, 256, 0, stream>>>(hidden, w, bias, alphas_out);
    scan_kernel<<<1, 256, 0, stream>>>(alphas_out, token_num, cif_peak,
                                       fire_time, nfired);
    fill_kernel<<<BB * T1, 128, 0, stream>>>(hidden, alphas_out, cif_peak,
                                             fire_time, nfired, ae);
}